// Round 3
// baseline (561.224 us; speedup 1.0000x reference)
//
#include <hip/hip_runtime.h>
#include <hip/hip_bf16.h>
#include <hip/hip_cooperative_groups.h>

namespace cg = cooperative_groups;

typedef __attribute__((ext_vector_type(8))) unsigned short u16x8;
typedef __attribute__((ext_vector_type(4))) unsigned short u16x4;
typedef __attribute__((ext_vector_type(8))) short short8;
typedef __attribute__((ext_vector_type(4))) float floatx4;

#define BS 64
#define CIN 256
#define II 1024
#define OO 320
#define JJ 10
#define DD 32

__device__ __forceinline__ float b2f(unsigned short u) {
    union { unsigned int i; float f; } x; x.i = ((unsigned int)u) << 16; return x.f;
}
__device__ __forceinline__ unsigned short f2b(float f) {
    union { float f; unsigned int i; } x; x.f = f;
    unsigned int r = x.i + 0x7fffu + ((x.i >> 16) & 1u);
    return (unsigned short)(r >> 16);
}

// multi-output butterfly: 32 per-lane partials p[d] -> sum over 64 lanes.
// After: lane l (l<32) holds total for d = l&31.  (fallback kernels)
__device__ __forceinline__ float butterfly32(const float* p, int l) {
    float q16[16];
#pragma unroll
    for (int d = 0; d < 16; ++d) {
        float keep = (l & 1) ? p[2 * d + 1] : p[2 * d];
        float send = (l & 1) ? p[2 * d] : p[2 * d + 1];
        q16[d] = keep + __shfl_xor(send, 1);
    }
    float q8[8];
#pragma unroll
    for (int d = 0; d < 8; ++d) {
        float keep = (l & 2) ? q16[2 * d + 1] : q16[2 * d];
        float send = (l & 2) ? q16[2 * d] : q16[2 * d + 1];
        q8[d] = keep + __shfl_xor(send, 2);
    }
    float q4[4];
#pragma unroll
    for (int d = 0; d < 4; ++d) {
        float keep = (l & 4) ? q8[2 * d + 1] : q8[2 * d];
        float send = (l & 4) ? q8[2 * d] : q8[2 * d + 1];
        q4[d] = keep + __shfl_xor(send, 4);
    }
    float q2[2];
#pragma unroll
    for (int d = 0; d < 2; ++d) {
        float keep = (l & 8) ? q4[2 * d + 1] : q4[2 * d];
        float send = (l & 8) ? q4[2 * d] : q4[2 * d + 1];
        q2[d] = keep + __shfl_xor(send, 8);
    }
    float keep = (l & 16) ? q2[1] : q2[0];
    float send = (l & 16) ? q2[0] : q2[1];
    float q1 = keep + __shfl_xor(send, 16);
    q1 += __shfl_xor(q1, 32);
    return q1;
}

// 16-value multi-output butterfly over the 16-lane lm group (strides 1,2,4,8).
// After: lane with lm = l&15 holds sum over the 16 lm-lanes of p[lm].
__device__ __forceinline__ float butterfly16(const float* p, int l) {
    float q8[8];
#pragma unroll
    for (int d = 0; d < 8; ++d) {
        float keep = (l & 1) ? p[2 * d + 1] : p[2 * d];
        float send = (l & 1) ? p[2 * d] : p[2 * d + 1];
        q8[d] = keep + __shfl_xor(send, 1);
    }
    float q4[4];
#pragma unroll
    for (int d = 0; d < 4; ++d) {
        float keep = (l & 2) ? q8[2 * d + 1] : q8[2 * d];
        float send = (l & 2) ? q8[2 * d] : q8[2 * d + 1];
        q4[d] = keep + __shfl_xor(send, 2);
    }
    float q2[2];
#pragma unroll
    for (int d = 0; d < 2; ++d) {
        float keep = (l & 4) ? q4[2 * d + 1] : q4[2 * d];
        float send = (l & 4) ? q4[2 * d] : q4[2 * d + 1];
        q2[d] = keep + __shfl_xor(send, 4);
    }
    float keep = (l & 8) ? q2[1] : q2[0];
    float send = (l & 8) ? q2[0] : q2[1];
    return keep + __shfl_xor(send, 8);
}

// ---------- prep: W f32 [320][256] -> 64-o-chunk frag-linear bf16 Wl ----------
__global__ __launch_bounds__(256) void k_prepW(const float* __restrict__ W,
                                               unsigned short* __restrict__ Wl) {
    int gid = blockIdx.x * 256 + threadIdx.x;   // 40 blocks -> 10240
    int lm = gid & 15;
    int quad = (gid >> 4) & 3;
    int mtl = (gid >> 6) & 3;
    int ks = (gid >> 8) & 7;
    int oc = gid >> 11;
    const float* src = W + (size_t)(oc * 64 + mtl * 16 + lm) * CIN + ks * 32 + quad * 8;
    float4 v0 = *(const float4*)src;
    float4 v1 = *(const float4*)(src + 4);
    u16x8 u;
    u[0] = f2b(v0.x); u[1] = f2b(v0.y); u[2] = f2b(v0.z); u[3] = f2b(v0.w);
    u[4] = f2b(v1.x); u[5] = f2b(v1.y); u[6] = f2b(v1.z); u[7] = f2b(v1.w);
    *(u16x8*)(Wl + (size_t)gid * 8) = u;
}

// ============================================================================
//   FUSED COOPERATIVE MEGA-KERNEL v3
//   grid 4x64 = 256 blocks (1/CU), 1024 threads = 16 waves (4/EU, 128 regs).
//   Two 8-wave groups per block, each owns one 128-i subtile -> pk[40]/thread
//   (fits: pk 40 + bfrag 32 + acc/av 32 + addr < 128 -> no scratch spill).
//   W staged via global_load_lds into its own LDS ping-pong (0 staging VGPRs);
//   x tiles live in per-group LDS buffers.  Route passes share one code body.
// ============================================================================

// W chunk (32 KB, frag-linear) -> LDS dst via async global->LDS, 2 insts/wave.
__device__ __forceinline__ void stageW(const unsigned short* __restrict__ Wl,
                                       unsigned short* dst, int chunk, int t) {
    const int wv = t >> 6, l = t & 63;
#if defined(__has_builtin) && __has_builtin(__builtin_amdgcn_global_load_lds)
    const unsigned short* g = Wl + (size_t)chunk * 16384 + wv * 1024 + l * 8;
    unsigned short* d = dst + wv * 1024;                    // wave-uniform base
    __builtin_amdgcn_global_load_lds(
        (const __attribute__((address_space(1))) void*)g,
        (__attribute__((address_space(3))) void*)d, 16, 0, 0);
    __builtin_amdgcn_global_load_lds(
        (const __attribute__((address_space(1))) void*)(g + 512),
        (__attribute__((address_space(3))) void*)(d + 512), 16, 0, 0);
#else
    const u16x8* src = (const u16x8*)(Wl + (size_t)chunk * 16384);
    u16x8* dd = (u16x8*)dst;
    dd[t] = src[t];
    dd[t + 1024] = src[t + 1024];
#endif
}

// one routing pass: reduce 4 partial slices -> s -> squash v -> per-i delta
// (quad shuffles) -> b update -> thread-local softmax over j -> c*pred
// partials (lm butterfly + LDS atomics) -> per-block partial [ic][b][320].
__device__ __forceinline__ void route_pass(
        const float* __restrict__ srcpart, float scale, bool first,
        const unsigned (&pk)[40], float (&b_reg)[JJ], float* __restrict__ dstpart,
        float* sacc, float* v_lds, float* cf,
        int ic, int b, int t, int l, int lm, int quad) {
    if (t < OO) {
        float s = 0.f;
#pragma unroll
        for (int sl = 0; sl < 4; ++sl) s += srcpart[((size_t)sl * BS + b) * OO + t];
        sacc[t] = scale * s;
    }
    __syncthreads();
    if (t < JJ) {
        float n2 = 0.f;
#pragma unroll
        for (int d = 0; d < DD; ++d) { float v = sacc[t * DD + d]; n2 += v * v; }
        cf[t] = sqrtf(n2) / (1.0f + n2);
    }
    __syncthreads();
    if (t < OO) { v_lds[t] = sacc[t] * cf[t >> 5]; sacc[t] = 0.f; }
    __syncthreads();

    // delta[i][j] = sum_d v[j][d]*pred[i][j][d]; thread holds 8 d per j (quad)
    float dj[JJ];
#pragma unroll
    for (int j = 0; j < JJ; ++j) dj[j] = 0.f;
#pragma unroll
    for (int m = 0; m < 20; ++m) {       // o = m*16 + quad*4 + r
        float4 vv = *(const float4*)&v_lds[m * 16 + quad * 4];
        unsigned a0 = pk[2 * m], a1 = pk[2 * m + 1];
        dj[m >> 1] += b2f((unsigned short)(a0 & 0xffffu)) * vv.x
                    + b2f((unsigned short)(a0 >> 16)) * vv.y
                    + b2f((unsigned short)(a1 & 0xffffu)) * vv.z
                    + b2f((unsigned short)(a1 >> 16)) * vv.w;
    }
#pragma unroll
    for (int j = 0; j < JJ; ++j) {       // complete dot over quads
        float d = dj[j];
        d += __shfl_xor(d, 16);
        d += __shfl_xor(d, 32);
        b_reg[j] = first ? d : (b_reg[j] + d);
    }
    // thread-local softmax over j
    float mx = b_reg[0];
#pragma unroll
    for (int j = 1; j < JJ; ++j) mx = fmaxf(mx, b_reg[j]);
    float cj[JJ], Z = 0.f;
#pragma unroll
    for (int j = 0; j < JJ; ++j) { cj[j] = __expf(b_reg[j] - mx); Z += cj[j]; }
    float inv = 1.0f / Z;
    // psum[j][d] partial over block's 256 i (both groups add): 5 groups of 16
#pragma unroll
    for (int gq = 0; gq < 5; ++gq) {
        float v16[16];
#pragma unroll
        for (int mm = 0; mm < 4; ++mm) {
            int m = 4 * gq + mm;
            unsigned a0 = pk[2 * m], a1 = pk[2 * m + 1];
            float c = cj[m >> 1] * inv;
            v16[4 * mm + 0] = c * b2f((unsigned short)(a0 & 0xffffu));
            v16[4 * mm + 1] = c * b2f((unsigned short)(a0 >> 16));
            v16[4 * mm + 2] = c * b2f((unsigned short)(a1 & 0xffffu));
            v16[4 * mm + 3] = c * b2f((unsigned short)(a1 >> 16));
        }
        float q = butterfly16(v16, l);
        atomicAdd(&sacc[gq * 64 + (lm >> 2) * 16 + quad * 4 + (lm & 3)], q);
    }
    __syncthreads();
    if (t < OO) dstpart[((size_t)ic * BS + b) * OO + t] = sacc[t];
}

__global__ __launch_bounds__(1024, 4) void k_mega(
        const float* __restrict__ x, const unsigned short* __restrict__ Wl,
        const float* __restrict__ Wb, float* __restrict__ s1part,
        float* __restrict__ psum1, float* __restrict__ psum2,
        float* __restrict__ out) {
    __shared__ unsigned short xb[2][16896];     // 67,584 B (x tile per group)
    __shared__ unsigned short wbuf[2][16384];   // 65,536 B (W chunk ping-pong)
    __shared__ float Wb_lds[OO];
    __shared__ float sacc[OO];
    __shared__ __align__(16) float v_lds[OO];
    __shared__ float cf[16];                    // total ~137 KB -> 1 block/CU

    cg::grid_group gg = cg::this_grid();

    const int ic = blockIdx.x, b = blockIdx.y;  // ic in [0,4)
    const int t = threadIdx.x;
    const int g = t >> 9, tt = t & 511;         // group 0/1, idx within group
    const int w = tt >> 6;                      // wave-in-group 0..7
    const int l = t & 63, lm = l & 15, quad = l >> 4;
    const int i0 = ic * 256 + g * 128;          // this group's 128-i subtile

    if (t < OO) { Wb_lds[t] = Wb[t]; sacc[t] = 0.f; }

    // W chunk 0 prefetch (completion covered by first staging barrier)
    stageW(Wl, wbuf[1], 0, t);

    // ---- stage x (both groups concurrently) in two K-halves; build B-frags ----
    short8 bfrag[8];
    const int crow = tt >> 5, f4 = tt & 31;
#pragma unroll
    for (int kc = 0; kc < 2; ++kc) {
        float4 fr[8];
#pragma unroll
        for (int p = 0; p < 8; ++p) {
            int c = kc * 128 + p * 16 + crow;
            fr[p] = *(const float4*)(x + ((size_t)b * CIN + c) * II + i0 + 4 * f4);
        }
#pragma unroll
        for (int p = 0; p < 8; ++p) {
            int cl = p * 16 + crow;
            u16x4 u;
            u[0] = f2b(fr[p].x); u[1] = f2b(fr[p].y); u[2] = f2b(fr[p].z); u[3] = f2b(fr[p].w);
            *(u16x4*)&xb[g][cl * 132 + 4 * f4] = u;
        }
        __syncthreads();
#pragma unroll
        for (int k2 = 0; k2 < 4; ++k2) {
            short8 f;
#pragma unroll
            for (int j = 0; j < 8; ++j)
                f[j] = (short)xb[g][(k2 * 32 + quad * 8 + j) * 132 + w * 16 + lm];
            bfrag[kc * 4 + k2] = f;
        }
        __syncthreads();
    }

    // ---- GEMM o-chunk loop (unrolled -> pk indices static) ----
    unsigned pk[40];
#pragma unroll
    for (int oc = 0; oc < 5; ++oc) {
        if (oc < 4) stageW(Wl, wbuf[oc & 1], oc + 1, t);
        const unsigned short* ab = wbuf[(oc + 1) & 1];
        floatx4 acc[4] = {};
#pragma unroll
        for (int ks = 0; ks < 8; ++ks)
#pragma unroll
            for (int mtl = 0; mtl < 4; ++mtl) {
                short8 af = *(const short8*)(ab + (size_t)(((ks * 4 + mtl) * 4 + quad) * 16 + lm) * 8);
                acc[mtl] = __builtin_amdgcn_mfma_f32_16x16x32_bf16(af, bfrag[ks], acc[mtl], 0, 0, 0);
            }
        float av[16];
#pragma unroll
        for (int mtl = 0; mtl < 4; ++mtl) {
            int ob = oc * 64 + mtl * 16 + quad * 4;
#pragma unroll
            for (int r = 0; r < 4; ++r) av[mtl * 4 + r] = acc[mtl][r] + Wb_lds[ob + r];
            pk[oc * 8 + mtl * 2 + 0] =
                (unsigned)f2b(av[mtl * 4 + 0]) | ((unsigned)f2b(av[mtl * 4 + 1]) << 16);
            pk[oc * 8 + mtl * 2 + 1] =
                (unsigned)f2b(av[mtl * 4 + 2]) | ((unsigned)f2b(av[mtl * 4 + 3]) << 16);
        }
        // s1 partial: sum biased f32 pred over this wave's 16 i -> LDS atomic
        float q = butterfly16(av, l);
        atomicAdd(&sacc[oc * 64 + (lm >> 2) * 16 + quad * 4 + (lm & 3)], q);
        __syncthreads();
    }

    // per-block s1 partial (sum over 256 i, bias included)
    if (t < OO) s1part[((size_t)ic * BS + b) * OO + t] = sacc[t];

    // ---- routing passes (shared body; loop NOT unrolled to keep code small) ----
    float b_reg[JJ];
#pragma unroll 1
    for (int pass = 0; pass < 2; ++pass) {
        __threadfence();
        gg.sync();
        route_pass(pass ? psum1 : s1part, pass ? 1.0f : 0.1f, pass == 0,
                   pk, b_reg, pass ? psum2 : psum1,
                   sacc, v_lds, cf, ic, b, t, l, lm, quad);
    }
    __threadfence();
    gg.sync();

    // ---- final squash + output (one block per batch) ----
    if (ic == 0) {
        if (t < OO) {
            float s = 0.f;
#pragma unroll
            for (int sl = 0; sl < 4; ++sl) s += psum2[((size_t)sl * BS + b) * OO + t];
            sacc[t] = s;
        }
        __syncthreads();
        if (t < JJ) {
            float n2 = 0.f;
#pragma unroll
            for (int d = 0; d < DD; ++d) { float v = sacc[t * DD + d]; n2 += v * v; }
            cf[t] = sqrtf(n2) / (1.0f + n2);
        }
        __syncthreads();
        if (t < OO) out[b * OO + t] = sacc[t] * cf[t >> 5];
    }
}

// ============================================================================
//            FALLBACK: verified 6-kernel pipeline (unchanged)
// ============================================================================

__global__ __launch_bounds__(512) void k_gemm8(const float* __restrict__ x,
                                               const unsigned short* __restrict__ Wl,
                                               const float* __restrict__ Wb,
                                               unsigned short* __restrict__ pred,
                                               float* __restrict__ psumC) {
    __shared__ unsigned short buf[2][16896];
    __shared__ float Wb_lds[OO];

    const int ic = blockIdx.x, b = blockIdx.y;
    const int t = threadIdx.x, w = t >> 6, l = t & 63;
    const int lm = l & 15, quad = l >> 4;
    const int i0 = ic * 128;

    if (t < OO) Wb_lds[t] = Wb[t];

    {
        const u16x8* src = (const u16x8*)Wl;
        u16x8* dst = (u16x8*)buf[1];
        dst[t] = src[t];
        dst[t + 512] = src[t + 512];
        dst[t + 1024] = src[t + 1024];
        dst[t + 1536] = src[t + 1536];
    }

    short8 bfrag[8];
    float csum[2];
    const int crow = t >> 5, f4 = t & 31;
    const int cs_c = t >> 2, cs_seg = t & 3;
#pragma unroll
    for (int kc = 0; kc < 2; ++kc) {
        float4 fr[8];
#pragma unroll
        for (int p = 0; p < 8; ++p) {
            int c = kc * 128 + p * 16 + crow;
            fr[p] = *(const float4*)(x + ((size_t)b * CIN + c) * II + i0 + 4 * f4);
        }
#pragma unroll
        for (int p = 0; p < 8; ++p) {
            int cl = p * 16 + crow;
            u16x4 u;
            u[0] = f2b(fr[p].x); u[1] = f2b(fr[p].y); u[2] = f2b(fr[p].z); u[3] = f2b(fr[p].w);
            *(u16x4*)&buf[0][cl * 132 + 4 * f4] = u;
        }
        __syncthreads();
#pragma unroll
        for (int k2 = 0; k2 < 4; ++k2) {
            short8 f;
#pragma unroll
            for (int j = 0; j < 8; ++j)
                f[j] = (short)buf[0][(k2 * 32 + quad * 8 + j) * 132 + w * 16 + lm];
            bfrag[kc * 4 + k2] = f;
        }
        {
            float cs = 0.f;
#pragma unroll
            for (int q = 0; q < 8; ++q) {
                u16x4 u = *(const u16x4*)&buf[0][cs_c * 132 + cs_seg * 32 + q * 4];
                cs += b2f(u[0]) + b2f(u[1]) + b2f(u[2]) + b2f(u[3]);
            }
            cs += __shfl_xor(cs, 1);
            cs += __shfl_xor(cs, 2);
            csum[kc] = cs;
        }
        __syncthreads();
    }
    if (cs_seg == 0) {
        size_t cbase = ((size_t)ic * BS + b) * CIN;
        psumC[cbase + cs_c] = csum[0];
        psumC[cbase + 128 + cs_c] = csum[1];
    }

    const size_t predrow = ((size_t)b * II + i0 + w * 16 + lm) * OO;
#pragma unroll 1
    for (int oc = 0; oc < 5; ++oc) {
        if (oc < 4) {
            const u16x8* src = (const u16x8*)Wl + (size_t)(oc + 1) * 2048;
            u16x8* dst = (u16x8*)buf[oc & 1];
            dst[t] = src[t];
            dst[t + 512] = src[t + 512];
            dst[t + 1024] = src[t + 1024];
            dst[t + 1536] = src[t + 1536];
        }
        const unsigned short* ab = buf[(oc + 1) & 1];
        floatx4 acc[4] = {};
#pragma unroll
        for (int ks = 0; ks < 8; ++ks)
#pragma unroll
            for (int mtl = 0; mtl < 4; ++mtl) {
                short8 af = *(const short8*)(ab + (size_t)(((ks * 4 + mtl) * 4 + quad) * 16 + lm) * 8);
                acc[mtl] = __builtin_amdgcn_mfma_f32_16x16x32_bf16(af, bfrag[ks], acc[mtl], 0, 0, 0);
            }
#pragma unroll
        for (int mtl = 0; mtl < 4; ++mtl) {
            int ob = oc * 64 + mtl * 16 + quad * 4;
            u16x4 sv;
#pragma unroll
            for (int r = 0; r < 4; ++r) sv[r] = f2b(acc[mtl][r] + Wb_lds[ob + r]);
            *(u16x4*)(pred + predrow + ob) = sv;
        }
        __syncthreads();
    }
}

__global__ __launch_bounds__(320) void k_gemv(const float* __restrict__ psumC,
                                              const float* __restrict__ W,
                                              const float* __restrict__ Wb,
                                              float* __restrict__ s1) {
    __shared__ float y_lds[CIN];
    const int b = blockIdx.x, t = threadIdx.x;
    if (t < CIN) {
        float s = 0.f;
#pragma unroll
        for (int sl = 0; sl < 8; ++sl) s += psumC[((size_t)sl * BS + b) * CIN + t];
        y_lds[t] = s;
    }
    __syncthreads();
    const float* wr = W + (size_t)t * CIN;
    float acc = 0.f;
#pragma unroll 4
    for (int c = 0; c < CIN; c += 4) {
        float4 wv = *(const float4*)(wr + c);
        acc += wv.x * y_lds[c] + wv.y * y_lds[c + 1] + wv.z * y_lds[c + 2] + wv.w * y_lds[c + 3];
    }
    s1[(size_t)b * OO + t] = 0.1f * (acc + 1024.0f * Wb[t]);
}

__global__ __launch_bounds__(640) void k_route1(const float* __restrict__ s1,
                                                const unsigned short* __restrict__ pred,
                                                float* __restrict__ blogG,
                                                float* __restrict__ psum1) {
    __shared__ float s_lds[OO];
    __shared__ float v_lds[OO];
    __shared__ float cf[JJ];
    __shared__ float dbuf[JJ][128];

    const int ic = blockIdx.x, b = blockIdx.y;
    const int t = threadIdx.x, w = t >> 6, l = t & 63;

    u16x8 va[4], vb[4];
    {
        const unsigned short* p0 = pred + ((size_t)b * II + ic * 128 + 2 * l) * OO + w * DD;
#pragma unroll
        for (int q = 0; q < 4; ++q) {
            va[q] = *(const u16x8*)(p0 + q * 8);
            vb[q] = *(const u16x8*)(p0 + OO + q * 8);
        }
    }

    if (t < OO) s_lds[t] = s1[(size_t)b * OO + t];
    __syncthreads();
    if (t < JJ) {
        float n2 = 0.f;
#pragma unroll
        for (int d = 0; d < DD; ++d) { float v = s_lds[t * DD + d]; n2 += v * v; }
        cf[t] = sqrtf(n2) / (1.0f + n2);
    }
    __syncthreads();
    if (t < OO) v_lds[t] = s_lds[t] * cf[t >> 5];
    __syncthreads();

    float d0 = 0.f, d1 = 0.f;
#pragma unroll
    for (int q = 0; q < 4; ++q)
#pragma unroll
        for (int e = 0; e < 8; ++e) {
            float vv = v_lds[w * DD + q * 8 + e];
            d0 += vv * b2f(va[q][e]);
            d1 += vv * b2f(vb[q][e]);
        }
    *(float2*)(blogG + ((size_t)b * JJ + w) * II + ic * 128 + 2 * l) = make_float2(d0, d1);
    dbuf[w][2 * l] = d0; dbuf[w][2 * l + 1] = d1;
    __syncthreads();

    if (t < 128) {
        float lg[JJ];
#pragma unroll
        for (int j = 0; j < JJ; ++j) lg[j] = dbuf[j][t];
        float m = lg[0];
#pragma unroll
        for (int j = 1; j < JJ; ++j) m = fmaxf(m, lg[j]);
        float Z = 0.f, c[JJ];
#pragma unroll
        for (int j = 0; j < JJ; ++j) { c[j] = __expf(lg[j] - m); Z += c[j]; }
        float inv = 1.0f / Z;
#pragma unroll
        for (int j = 0; j < JJ; ++j) dbuf[j][t] = c[j] * inv;
    }
    __syncthreads();

    float c0 = dbuf[w][2 * l], c1 = dbuf[w][2 * l + 1];
    float p[DD];
#pragma unroll
    for (int q = 0; q < 4; ++q)
#pragma unroll
        for (int e = 0; e < 8; ++e)
            p[q * 8 + e] = c0 * b2f(va[q][e]) + c1 * b2f(vb[q][e]);
    float s = butterfly32(p, l);
    if (l < 32) psum1[((size_t)ic * BS + b) * OO + w * DD + l] = s;
}

__global__ __launch_bounds__(640) void k_route2(const float* __restrict__ psum1,
                                                const unsigned short* __restrict__ pred,
                                                const float* __restrict__ blogG,
                                                float* __restrict__ psum2) {
    __shared__ float s_lds[OO];
    __shared__ float v_lds[OO];
    __shared__ float cf[JJ];
    __shared__ float dbuf[JJ][128];

    const int ic = blockIdx.x, b = blockIdx.y;
    const int t = threadIdx.x, w = t >> 6, l = t & 63;

    u16x8 va[4], vb[4];
    {
        const unsigned short* p0 = pred + ((size_t)b * II + ic * 128 + 2 * l) * OO + w * DD;
#pragma unroll
        for (int q = 0; q < 4; ++q) {
            va[q] = *(const u16x8*)(p0 + q * 8);
            vb[q] = *(const u16x8*)(p0 + OO + q * 8);
        }
    }

    if (t < OO) {
        float s = 0.f;
#pragma unroll
        for (int sl = 0; sl < 8; ++sl) s += psum1[((size_t)sl * BS + b) * OO + t];
        s_lds[t] = s;
    }
    __syncthreads();
    if (t < JJ) {
        float n2 = 0.f;
#pragma unroll
        for (int d = 0; d < DD; ++d) { float v = s_lds[t * DD + d]; n2 += v * v; }
        cf[t] = sqrtf(n2) / (1.0f + n2);
    }
    __syncthreads();
    if (t < OO) v_lds[t] = s_lds[t] * cf[t >> 5];
    __syncthreads();

    float d0 = 0.f, d1 = 0.f;
#pragma unroll
    for (int q = 0; q < 4; ++q)
#pragma unroll
        for (int e = 0; e < 8; ++e) {
            float vv = v_lds[w * DD + q * 8 + e];
            d0 += vv * b2f(va[q][e]);
            d1 += vv * b2f(vb[q][e]);
        }
    float2 bl = *(const float2*)(blogG + ((size_t)b * JJ + w) * II + ic * 128 + 2 * l);
    dbuf[w][2 * l] = bl.x + d0; dbuf[w][2 * l + 1] = bl.y + d1;
    __syncthreads();

    if (t < 128) {
        float lg[JJ];
#pragma unroll
        for (int j = 0; j < JJ; ++j) lg[j] = dbuf[j][t];
        float m = lg[0];
#pragma unroll
        for (int j = 1; j < JJ; ++j) m = fmaxf(m, lg[j]);
        float Z = 0.f, c[JJ];
#pragma unroll
        for (int j = 0; j < JJ; ++j) { c[j] = __expf(lg[j] - m); Z += c[j]; }
        float inv = 1.0f / Z;
#pragma unroll
        for (int j = 0; j < JJ; ++j) dbuf[j][t] = c[j] * inv;
    }
    __syncthreads();

    float c0 = dbuf[w][2 * l], c1 = dbuf[w][2 * l + 1];
    float p[DD];
#pragma unroll
    for (int q = 0; q < 4; ++q)
#pragma unroll
        for (int e = 0; e < 8; ++e)
            p[q * 8 + e] = c0 * b2f(va[q][e]) + c1 * b2f(vb[q][e]);
    float s = butterfly32(p, l);
    if (l < 32) psum2[((size_t)ic * BS + b) * OO + w * DD + l] = s;
}

__global__ __launch_bounds__(320) void k_final2(const float* __restrict__ psum2,
                                                float* __restrict__ out) {
    __shared__ float s_lds[OO];
    __shared__ float cf[JJ];
    int b = blockIdx.x, t = threadIdx.x;
    float s = 0.f;
#pragma unroll
    for (int sl = 0; sl < 8; ++sl) s += psum2[((size_t)sl * BS + b) * OO + t];
    s_lds[t] = s;
    __syncthreads();
    if (t < JJ) {
        float n2 = 0.f;
#pragma unroll
        for (int d = 0; d < DD; ++d) { float v = s_lds[t * DD + d]; n2 += v * v; }
        cf[t] = sqrtf(n2) / (1.0f + n2);
    }
    __syncthreads();
    out[b * OO + t] = s_lds[t] * cf[t >> 5];
}

extern "C" void kernel_launch(void* const* d_in, const int* in_sizes, int n_in,
                              void* d_out, int out_size, void* d_ws, size_t ws_size,
                              hipStream_t stream) {
    const float* x  = (const float*)d_in[0];  // [64][256][1024] f32
    const float* W  = (const float*)d_in[1];  // [320][256] f32
    const float* Wb = (const float*)d_in[2];  // [320] f32

    char* ws = (char*)d_ws;
    unsigned short* pred = (unsigned short*)ws;              // 41,943,040 B  (fallback only)
    unsigned short* Wl   = (unsigned short*)(ws + 41943040); // 163,840 B
    float* psumC = (float*)(ws + 42106880);                  // 524,288 B (fallback only)
    float* s1    = (float*)(ws + 42631168);                  // 81,920 B  (fallback only)
    float* psum1 = (float*)(ws + 42713088);                  // 655,360 B
    float* psum2 = (float*)(ws + 43368448);                  // 655,360 B
    float* blogG = (float*)(ws + 44023808);                  // 2,621,440 B (fallback only)
    float* s1part = (float*)(ws + 46645248);                 // 655,360 B (mega only)

    k_prepW<<<40, 256, 0, stream>>>(W, Wl);

    // primary: single cooperative fused kernel, 256 blocks x 1024 threads
    {
        const float* a0 = x;
        const unsigned short* a1 = Wl;
        const float* a2 = Wb;
        float* a3 = s1part;
        float* a4 = psum1;
        float* a5 = psum2;
        float* a6 = (float*)d_out;
        void* kargs[] = {&a0, &a1, &a2, &a3, &a4, &a5, &a6};
        hipError_t e = hipLaunchCooperativeKernel(k_mega, dim3(4, BS), dim3(1024, 1, 1),
                                                  kargs, 0, stream);
        if (e == hipSuccess) return;
    }

    // fallback: verified 6-kernel pipeline
    k_gemm8<<<dim3(8, BS), 512, 0, stream>>>(x, Wl, Wb, pred, psumC);
    k_gemv<<<BS, 320, 0, stream>>>(psumC, W, Wb, s1);
    k_route1<<<dim3(8, BS), 640, 0, stream>>>(s1, pred, blogG, psum1);
    k_route2<<<dim3(8, BS), 640, 0, stream>>>(psum1, pred, blogG, psum2);
    k_final2<<<BS, 320, 0, stream>>>(psum2, (float*)d_out);
}

// Round 4
// 146.170 us; speedup vs baseline: 3.8395x; 3.8395x over previous
//
#include <hip/hip_runtime.h>
#include <hip/hip_bf16.h>

typedef __attribute__((ext_vector_type(8))) unsigned short u16x8;
typedef __attribute__((ext_vector_type(4))) unsigned short u16x4;
typedef __attribute__((ext_vector_type(8))) short short8;
typedef __attribute__((ext_vector_type(4))) float floatx4;

#define BS 64
#define CIN 256
#define II 1024
#define OO 320
#define JJ 10
#define DD 32

__device__ __forceinline__ float b2f(unsigned short u) {
    union { unsigned int i; float f; } x; x.i = ((unsigned int)u) << 16; return x.f;
}
__device__ __forceinline__ unsigned short f2b(float f) {
    union { float f; unsigned int i; } x; x.f = f;
    unsigned int r = x.i + 0x7fffu + ((x.i >> 16) & 1u);
    return (unsigned short)(r >> 16);
}

// multi-output butterfly: 32 per-lane partials p[d] -> sum over 64 lanes.
// After: lane l (l<32) holds total for d = l&31. 32 shuffles total.
__device__ __forceinline__ float butterfly32(const float* p, int l) {
    float q16[16];
#pragma unroll
    for (int d = 0; d < 16; ++d) {
        float keep = (l & 1) ? p[2 * d + 1] : p[2 * d];
        float send = (l & 1) ? p[2 * d] : p[2 * d + 1];
        q16[d] = keep + __shfl_xor(send, 1);
    }
    float q8[8];
#pragma unroll
    for (int d = 0; d < 8; ++d) {
        float keep = (l & 2) ? q16[2 * d + 1] : q16[2 * d];
        float send = (l & 2) ? q16[2 * d] : q16[2 * d + 1];
        q8[d] = keep + __shfl_xor(send, 2);
    }
    float q4[4];
#pragma unroll
    for (int d = 0; d < 4; ++d) {
        float keep = (l & 4) ? q8[2 * d + 1] : q8[2 * d];
        float send = (l & 4) ? q8[2 * d] : q8[2 * d + 1];
        q4[d] = keep + __shfl_xor(send, 4);
    }
    float q2[2];
#pragma unroll
    for (int d = 0; d < 2; ++d) {
        float keep = (l & 8) ? q4[2 * d + 1] : q4[2 * d];
        float send = (l & 8) ? q4[2 * d] : q4[2 * d + 1];
        q2[d] = keep + __shfl_xor(send, 8);
    }
    float keep = (l & 16) ? q2[1] : q2[0];
    float send = (l & 16) ? q2[0] : q2[1];
    float q1 = keep + __shfl_xor(send, 16);
    q1 += __shfl_xor(q1, 32);
    return q1;
}

// ---------- prep: W f32 [320][256] -> 64-o-chunk frag-linear bf16 Wl ----------
__global__ __launch_bounds__(256) void k_prepW(const float* __restrict__ W,
                                               unsigned short* __restrict__ Wl) {
    int gid = blockIdx.x * 256 + threadIdx.x;   // 40 blocks -> 10240
    int lm = gid & 15;
    int quad = (gid >> 4) & 3;
    int mtl = (gid >> 6) & 3;
    int ks = (gid >> 8) & 7;
    int oc = gid >> 11;
    const float* src = W + (size_t)(oc * 64 + mtl * 16 + lm) * CIN + ks * 32 + quad * 8;
    float4 v0 = *(const float4*)src;
    float4 v1 = *(const float4*)(src + 4);
    u16x8 u;
    u[0] = f2b(v0.x); u[1] = f2b(v0.y); u[2] = f2b(v0.z); u[3] = f2b(v0.w);
    u[4] = f2b(v1.x); u[5] = f2b(v1.y); u[6] = f2b(v1.z); u[7] = f2b(v1.w);
    *(u16x8*)(Wl + (size_t)gid * 8) = u;
}

// ============================================================================
// pred layout (NEW, i-minor for coalescing):
//   pred[(b*8+ic)*40960 + mprime*512 + iprime*4 + r]
//   where o = mprime*4 + r  (mprime 0..79, r 0..3), iprime = i - ic*128.
// GEMM store: u16x4 per lane at lm*8-byte stride -> 4x128B segments/wave.
// Route load: u16x8 per lane at l*16-byte stride -> fully coalesced 1KB/inst.
// ============================================================================

// ---------- K1: GEMM -> pred (coalesced layout), ping-pong W chunks, colsum fused ----------
// grid (8 ic, 64 b) x 512 thr (8 waves). Wave w owns i = ic*128 + w*16 + lm.
__global__ __launch_bounds__(512) void k_gemm8(const float* __restrict__ x,
                                               const unsigned short* __restrict__ Wl,
                                               const float* __restrict__ Wb,
                                               unsigned short* __restrict__ pred,
                                               float* __restrict__ psumC) {
    __shared__ unsigned short buf[2][16896];   // 2 x 33,792 B (x-tile, then W ping-pong)
    __shared__ float Wb_lds[OO];               // -> 68.9 KB total (2 blocks/CU)

    const int ic = blockIdx.x, b = blockIdx.y;
    const int t = threadIdx.x, w = t >> 6, l = t & 63;
    const int lm = l & 15, quad = l >> 4;
    const int i0 = ic * 128;

    if (t < OO) Wb_lds[t] = Wb[t];

    // W chunk 0 -> buf[1] (covered by first staging barrier)
    {
        const u16x8* src = (const u16x8*)Wl;
        u16x8* dst = (u16x8*)buf[1];
        dst[t] = src[t];
        dst[t + 512] = src[t + 512];
        dst[t + 1024] = src[t + 1024];
        dst[t + 1536] = src[t + 1536];
    }

    // ---- stage x in two K-halves through buf[0]; build B-frags + colsum ----
    short8 bfrag[8];
    float csum[2];
    const int crow = t >> 5, f4 = t & 31;
    const int cs_c = t >> 2, cs_seg = t & 3;
#pragma unroll
    for (int kc = 0; kc < 2; ++kc) {
        float4 fr[8];
#pragma unroll
        for (int p = 0; p < 8; ++p) {
            int c = kc * 128 + p * 16 + crow;
            fr[p] = *(const float4*)(x + ((size_t)b * CIN + c) * II + i0 + 4 * f4);
        }
#pragma unroll
        for (int p = 0; p < 8; ++p) {
            int cl = p * 16 + crow;
            u16x4 u;
            u[0] = f2b(fr[p].x); u[1] = f2b(fr[p].y); u[2] = f2b(fr[p].z); u[3] = f2b(fr[p].w);
            *(u16x4*)&buf[0][cl * 132 + 4 * f4] = u;
        }
        __syncthreads();
#pragma unroll
        for (int k2 = 0; k2 < 4; ++k2) {
            short8 f;
#pragma unroll
            for (int j = 0; j < 8; ++j)
                f[j] = (short)buf[0][(k2 * 32 + quad * 8 + j) * 132 + w * 16 + lm];
            bfrag[kc * 4 + k2] = f;   // static indices: stays in VGPRs
        }
        {
            float cs = 0.f;
#pragma unroll
            for (int q = 0; q < 8; ++q) {
                u16x4 u = *(const u16x4*)&buf[0][cs_c * 132 + cs_seg * 32 + q * 4];
                cs += b2f(u[0]) + b2f(u[1]) + b2f(u[2]) + b2f(u[3]);
            }
            cs += __shfl_xor(cs, 1);
            cs += __shfl_xor(cs, 2);
            csum[kc] = cs;
        }
        __syncthreads();   // frag/colsum reads done before restage / oc-loop
    }
    if (cs_seg == 0) {
        size_t cbase = ((size_t)ic * BS + b) * CIN;
        psumC[cbase + cs_c] = csum[0];
        psumC[cbase + 128 + cs_c] = csum[1];
    }

    // ---- o-chunk loop: MFMA on buf[(oc+1)&1], stage next chunk into buf[oc&1]; 1 barrier/oc ----
    // NEW coalesced pred store base: this thread's i' = w*16+lm slot.
    const size_t predbase = ((size_t)(b * 8 + ic)) * 40960 + (size_t)(w * 16 + lm) * 4;
#pragma unroll 1
    for (int oc = 0; oc < 5; ++oc) {
        if (oc < 4) {
            const u16x8* src = (const u16x8*)Wl + (size_t)(oc + 1) * 2048;
            u16x8* dst = (u16x8*)buf[oc & 1];
            dst[t] = src[t];
            dst[t + 512] = src[t + 512];
            dst[t + 1024] = src[t + 1024];
            dst[t + 1536] = src[t + 1536];
        }
        const unsigned short* ab = buf[(oc + 1) & 1];
        floatx4 acc[4] = {};
#pragma unroll
        for (int ks = 0; ks < 8; ++ks)
#pragma unroll
            for (int mtl = 0; mtl < 4; ++mtl) {
                short8 af = *(const short8*)(ab + (size_t)(((ks * 4 + mtl) * 4 + quad) * 16 + lm) * 8);
                acc[mtl] = __builtin_amdgcn_mfma_f32_16x16x32_bf16(af, bfrag[ks], acc[mtl], 0, 0, 0);
            }
#pragma unroll
        for (int mtl = 0; mtl < 4; ++mtl) {
            int ob = oc * 64 + mtl * 16 + quad * 4;       // o = ob + r
            int mprime = oc * 16 + mtl * 4 + quad;        // o = mprime*4 + r
            u16x4 sv;
#pragma unroll
            for (int r = 0; r < 4; ++r) sv[r] = f2b(acc[mtl][r] + Wb_lds[ob + r]);
            *(u16x4*)(pred + predbase + (size_t)mprime * 512) = sv;
        }
        __syncthreads();
    }
}

// ---------- GEMV: s1[b,o] = 0.1*(sum_c W[o,c]*colsum[b,c] + 1024*Wb[o]) ----------
__global__ __launch_bounds__(320) void k_gemv(const float* __restrict__ psumC,
                                              const float* __restrict__ W,
                                              const float* __restrict__ Wb,
                                              float* __restrict__ s1) {
    __shared__ float y_lds[CIN];
    const int b = blockIdx.x, t = threadIdx.x;
    if (t < CIN) {
        float s = 0.f;
#pragma unroll
        for (int sl = 0; sl < 8; ++sl) s += psumC[((size_t)sl * BS + b) * CIN + t];
        y_lds[t] = s;
    }
    __syncthreads();
    const float* wr = W + (size_t)t * CIN;
    float acc = 0.f;
#pragma unroll 4
    for (int c = 0; c < CIN; c += 4) {
        float4 wv = *(const float4*)(wr + c);
        acc += wv.x * y_lds[c] + wv.y * y_lds[c + 1] + wv.z * y_lds[c + 2] + wv.w * y_lds[c + 3];
    }
    s1[(size_t)b * OO + t] = 0.1f * (acc + 1024.0f * Wb[t]);
}

// ---------- route pass 1: coalesced pred loads; lane owns 2 i; butterfly wsum ----------
// grid (8 ic, 64 b) x 640 thr (wave w = capsule j).
// Ld[dq] (dq=0..7): u16x8 covering o=(j*8+dq)*4..+3 for i=2l (elems 0..3) and
// i=2l+1 (elems 4..7).  d = dq*4+e, o = j*32+d.
__global__ __launch_bounds__(640) void k_route1(const float* __restrict__ s1,
                                                const unsigned short* __restrict__ pred,
                                                float* __restrict__ blogG,
                                                float* __restrict__ psum1) {
    __shared__ float s_lds[OO];
    __shared__ float v_lds[OO];
    __shared__ float cf[JJ];
    __shared__ float dbuf[JJ][128];

    const int ic = blockIdx.x, b = blockIdx.y;
    const int t = threadIdx.x, w = t >> 6, l = t & 63;

    u16x8 Ld[8];
    {
        const unsigned short* p0 = pred + ((size_t)(b * 8 + ic)) * 40960
                                 + (size_t)(w * 8) * 512 + 8 * l;
#pragma unroll
        for (int dq = 0; dq < 8; ++dq)
            Ld[dq] = *(const u16x8*)(p0 + (size_t)dq * 512);
    }

    if (t < OO) s_lds[t] = s1[(size_t)b * OO + t];
    __syncthreads();
    if (t < JJ) {
        float n2 = 0.f;
#pragma unroll
        for (int d = 0; d < DD; ++d) { float v = s_lds[t * DD + d]; n2 += v * v; }
        cf[t] = sqrtf(n2) / (1.0f + n2);
    }
    __syncthreads();
    if (t < OO) v_lds[t] = s_lds[t] * cf[t >> 5];
    __syncthreads();

    float d0 = 0.f, d1 = 0.f;
#pragma unroll
    for (int dq = 0; dq < 8; ++dq)
#pragma unroll
        for (int e = 0; e < 4; ++e) {
            float vv = v_lds[w * DD + dq * 4 + e];
            d0 += vv * b2f(Ld[dq][e]);
            d1 += vv * b2f(Ld[dq][4 + e]);
        }
    *(float2*)(blogG + ((size_t)b * JJ + w) * II + ic * 128 + 2 * l) = make_float2(d0, d1);
    dbuf[w][2 * l] = d0; dbuf[w][2 * l + 1] = d1;
    __syncthreads();

    if (t < 128) {
        float lg[JJ];
#pragma unroll
        for (int j = 0; j < JJ; ++j) lg[j] = dbuf[j][t];
        float m = lg[0];
#pragma unroll
        for (int j = 1; j < JJ; ++j) m = fmaxf(m, lg[j]);
        float Z = 0.f, c[JJ];
#pragma unroll
        for (int j = 0; j < JJ; ++j) { c[j] = __expf(lg[j] - m); Z += c[j]; }
        float inv = 1.0f / Z;
#pragma unroll
        for (int j = 0; j < JJ; ++j) dbuf[j][t] = c[j] * inv;
    }
    __syncthreads();

    float c0 = dbuf[w][2 * l], c1 = dbuf[w][2 * l + 1];
    float p[DD];
#pragma unroll
    for (int dq = 0; dq < 8; ++dq)
#pragma unroll
        for (int e = 0; e < 4; ++e)
            p[dq * 4 + e] = c0 * b2f(Ld[dq][e]) + c1 * b2f(Ld[dq][4 + e]);
    float s = butterfly32(p, l);
    if (l < 32) psum1[((size_t)ic * BS + b) * OO + w * DD + l] = s;
}

// ---------- route pass 2 ----------
__global__ __launch_bounds__(640) void k_route2(const float* __restrict__ psum1,
                                                const unsigned short* __restrict__ pred,
                                                const float* __restrict__ blogG,
                                                float* __restrict__ psum2) {
    __shared__ float s_lds[OO];
    __shared__ float v_lds[OO];
    __shared__ float cf[JJ];
    __shared__ float dbuf[JJ][128];

    const int ic = blockIdx.x, b = blockIdx.y;
    const int t = threadIdx.x, w = t >> 6, l = t & 63;

    u16x8 Ld[8];
    {
        const unsigned short* p0 = pred + ((size_t)(b * 8 + ic)) * 40960
                                 + (size_t)(w * 8) * 512 + 8 * l;
#pragma unroll
        for (int dq = 0; dq < 8; ++dq)
            Ld[dq] = *(const u16x8*)(p0 + (size_t)dq * 512);
    }

    if (t < OO) {
        float s = 0.f;
#pragma unroll
        for (int sl = 0; sl < 8; ++sl) s += psum1[((size_t)sl * BS + b) * OO + t];
        s_lds[t] = s;
    }
    __syncthreads();
    if (t < JJ) {
        float n2 = 0.f;
#pragma unroll
        for (int d = 0; d < DD; ++d) { float v = s_lds[t * DD + d]; n2 += v * v; }
        cf[t] = sqrtf(n2) / (1.0f + n2);
    }
    __syncthreads();
    if (t < OO) v_lds[t] = s_lds[t] * cf[t >> 5];
    __syncthreads();

    float d0 = 0.f, d1 = 0.f;
#pragma unroll
    for (int dq = 0; dq < 8; ++dq)
#pragma unroll
        for (int e = 0; e < 4; ++e) {
            float vv = v_lds[w * DD + dq * 4 + e];
            d0 += vv * b2f(Ld[dq][e]);
            d1 += vv * b2f(Ld[dq][4 + e]);
        }
    float2 bl = *(const float2*)(blogG + ((size_t)b * JJ + w) * II + ic * 128 + 2 * l);
    dbuf[w][2 * l] = bl.x + d0; dbuf[w][2 * l + 1] = bl.y + d1;
    __syncthreads();

    if (t < 128) {
        float lg[JJ];
#pragma unroll
        for (int j = 0; j < JJ; ++j) lg[j] = dbuf[j][t];
        float m = lg[0];
#pragma unroll
        for (int j = 1; j < JJ; ++j) m = fmaxf(m, lg[j]);
        float Z = 0.f, c[JJ];
#pragma unroll
        for (int j = 0; j < JJ; ++j) { c[j] = __expf(lg[j] - m); Z += c[j]; }
        float inv = 1.0f / Z;
#pragma unroll
        for (int j = 0; j < JJ; ++j) dbuf[j][t] = c[j] * inv;
    }
    __syncthreads();

    float c0 = dbuf[w][2 * l], c1 = dbuf[w][2 * l + 1];
    float p[DD];
#pragma unroll
    for (int dq = 0; dq < 8; ++dq)
#pragma unroll
        for (int e = 0; e < 4; ++e)
            p[dq * 4 + e] = c0 * b2f(Ld[dq][e]) + c1 * b2f(Ld[dq][4 + e]);
    float s = butterfly32(p, l);
    if (l < 32) psum2[((size_t)ic * BS + b) * OO + w * DD + l] = s;
}

// ---------- final: reduce psum2 (8 slices), squash, write f32 out ----------
__global__ __launch_bounds__(320) void k_final2(const float* __restrict__ psum2,
                                                float* __restrict__ out) {
    __shared__ float s_lds[OO];
    __shared__ float cf[JJ];
    int b = blockIdx.x, t = threadIdx.x;
    float s = 0.f;
#pragma unroll
    for (int sl = 0; sl < 8; ++sl) s += psum2[((size_t)sl * BS + b) * OO + t];
    s_lds[t] = s;
    __syncthreads();
    if (t < JJ) {
        float n2 = 0.f;
#pragma unroll
        for (int d = 0; d < DD; ++d) { float v = s_lds[t * DD + d]; n2 += v * v; }
        cf[t] = sqrtf(n2) / (1.0f + n2);
    }
    __syncthreads();
    out[b * OO + t] = s_lds[t] * cf[t >> 5];
}

extern "C" void kernel_launch(void* const* d_in, const int* in_sizes, int n_in,
                              void* d_out, int out_size, void* d_ws, size_t ws_size,
                              hipStream_t stream) {
    const float* x  = (const float*)d_in[0];  // [64][256][1024] f32
    const float* W  = (const float*)d_in[1];  // [320][256] f32
    const float* Wb = (const float*)d_in[2];  // [320] f32

    char* ws = (char*)d_ws;
    unsigned short* pred = (unsigned short*)ws;              // 41,943,040 B  [b][ic][o/4][i'][4]
    unsigned short* Wl   = (unsigned short*)(ws + 41943040); // 163,840 B  -> 42,106,880
    float* psumC = (float*)(ws + 42106880);                  // 524,288 B  -> 42,631,168
    float* s1    = (float*)(ws + 42631168);                  // 81,920 B   -> 42,713,088
    float* psum1 = (float*)(ws + 42713088);                  // 655,360 B  -> 43,368,448
    float* psum2 = (float*)(ws + 43368448);                  // 655,360 B  -> 44,023,808
    float* blogG = (float*)(ws + 44023808);                  // 2,621,440 B-> 46,645,248

    k_prepW<<<40, 256, 0, stream>>>(W, Wl);
    k_gemm8<<<dim3(8, BS), 512, 0, stream>>>(x, Wl, Wb, pred, psumC);
    k_gemv<<<BS, 320, 0, stream>>>(psumC, W, Wb, s1);
    k_route1<<<dim3(8, BS), 640, 0, stream>>>(s1, pred, blogG, psum1);
    k_route2<<<dim3(8, BS), 640, 0, stream>>>(psum1, pred, blogG, psum2);
    k_final2<<<BS, 320, 0, stream>>>(psum2, (float*)d_out);
}